// Round 3
// baseline (740.834 us; speedup 1.0000x reference)
//
#include <hip/hip_runtime.h>
#include <cstdint>
#include <cstddef>

// B=2, S=1024, D=512, NH=16 (chunk width), C=32 chunks.
// weights output (C,B,S,S) fp32 = 256 MiB written once, never re-read (PV fused).
// out_pre scramble: (c,b,m,h) -> [c>>4][(c&15)*64 + (m>>4)][(m&15)*32 + b*16 + h]

// ---------------------------------------------------------------------------
// NT GEMM body: P[M][512] = X[M][512] * W[512][512]^T   (tiles 64x64x32)
// ---------------------------------------------------------------------------
__device__ __forceinline__ void gemm_nt_body(const float* __restrict__ X,
                                             const float* __restrict__ W,
                                             float* __restrict__ P)
{
    __shared__ float As[32][68];
    __shared__ float Bs[32][68];
    const int t  = threadIdx.x;
    const int tx = t & 15, ty = t >> 4;
    const int m0 = blockIdx.y << 6;
    const int n0 = blockIdx.x << 6;
    float acc[4][4] = {};
    for (int k0 = 0; k0 < 512; k0 += 32) {
#pragma unroll
        for (int rep = 0; rep < 2; ++rep) {
            int f  = rep * 256 + t;
            int r  = f >> 3, c4 = f & 7;
            float4 xv = *(const float4*)(X + (size_t)(m0 + r) * 512 + k0 + c4 * 4);
            As[c4 * 4 + 0][r] = xv.x; As[c4 * 4 + 1][r] = xv.y;
            As[c4 * 4 + 2][r] = xv.z; As[c4 * 4 + 3][r] = xv.w;
            float4 wv = *(const float4*)(W + (size_t)(n0 + r) * 512 + k0 + c4 * 4);
            Bs[c4 * 4 + 0][r] = wv.x; Bs[c4 * 4 + 1][r] = wv.y;
            Bs[c4 * 4 + 2][r] = wv.z; Bs[c4 * 4 + 3][r] = wv.w;
        }
        __syncthreads();
#pragma unroll
        for (int kk = 0; kk < 32; ++kk) {
            float4 av = *(const float4*)(&As[kk][ty * 4]);
            float4 bv = *(const float4*)(&Bs[kk][tx * 4]);
            float a[4] = {av.x, av.y, av.z, av.w};
            float b[4] = {bv.x, bv.y, bv.z, bv.w};
#pragma unroll
            for (int i = 0; i < 4; ++i)
#pragma unroll
                for (int j = 0; j < 4; ++j)
                    acc[i][j] += a[i] * b[j];
        }
        __syncthreads();
    }
#pragma unroll
    for (int i = 0; i < 4; ++i) {
        float4 o = make_float4(acc[i][0], acc[i][1], acc[i][2], acc[i][3]);
        *(float4*)(P + (size_t)(m0 + ty * 4 + i) * 512 + n0 + tx * 4) = o;
    }
}

__global__ __launch_bounds__(256, 2) void proj3_kernel(
    const float* __restrict__ Q, const float* __restrict__ K, const float* __restrict__ V,
    const float* __restrict__ Wq, const float* __restrict__ Wk, const float* __restrict__ Wv,
    float* __restrict__ q, float* __restrict__ k, float* __restrict__ v)
{
    const float* X; const float* W; float* P;
    if (blockIdx.z == 0)      { X = Q; W = Wq; P = q; }
    else if (blockIdx.z == 1) { X = K; W = Wk; P = k; }
    else                      { X = V; W = Wv; P = v; }
    gemm_nt_body(X, W, P);
}

__global__ __launch_bounds__(256, 2) void outproj_kernel(
    const float* __restrict__ att, const float* __restrict__ Wo, float* __restrict__ out)
{
    gemm_nt_body(att, Wo, out);
}

// ---------------------------------------------------------------------------
// Fused scores + softmax + weights-write + PV.  v2: 2 rows/pass (16 passes),
// float4 n-mapping (n = i*256 + lane*4 + j) -> ds_read_b128 everywhere and
// float4 weights stores. Peak live regs ~90 -> no scratch spill (round-2 bug).
// Block = (c, b, 256-row tile), 512 threads (8 waves), grid = 256.
// LDS: khT[16][1024] + vsT[16][1024] + qs[256][16] = 144 KB (1 block/CU).
// PV reduction: 5-step reduce-scatter butterfly over 32 values + xor-32 add;
// lane L (L<32) ends holding att[r0 + (L>>4)][L&15] summed over all 64 lanes.
// ---------------------------------------------------------------------------
__global__ __launch_bounds__(512, 2) void attn_fused_kernel(
    const float* __restrict__ q, const float* __restrict__ k, const float* __restrict__ v,
    float* __restrict__ wts, float* __restrict__ att)
{
    __shared__ float khT[16][1024];
    __shared__ float vsT[16][1024];
    __shared__ float qs[256][16];
    const int t   = threadIdx.x;
    const int bid = blockIdx.x;       // 256 blocks
    const int mt  = bid & 3;          // 4 row tiles of 256
    const int cb  = bid >> 2;         // c*2 + b
    const int b   = cb & 1;
    const int c   = cb >> 1;
    const int m0  = mt << 8;

    const float* kb = k + (size_t)b * 524288 + c * 16;
    const float* vb = v + (size_t)b * 524288 + c * 16;
    const float* qb = q + (size_t)b * 524288 + (size_t)m0 * 512 + c * 16;

#pragma unroll
    for (int rep = 0; rep < 8; ++rep) {
        int f = rep * 512 + t;        // 4096 float4-slots
        int n = f >> 2, hq = f & 3;
        float4 kv = *(const float4*)(kb + (size_t)n * 512 + hq * 4);
        khT[hq*4+0][n] = kv.x; khT[hq*4+1][n] = kv.y;
        khT[hq*4+2][n] = kv.z; khT[hq*4+3][n] = kv.w;
        float4 vv = *(const float4*)(vb + (size_t)n * 512 + hq * 4);
        vsT[hq*4+0][n] = vv.x; vsT[hq*4+1][n] = vv.y;
        vsT[hq*4+2][n] = vv.z; vsT[hq*4+3][n] = vv.w;
    }
#pragma unroll
    for (int rep = 0; rep < 2; ++rep) {
        int f = rep * 512 + t;        // 1024 float4-slots
        int r = f >> 2, hq = f & 3;
        *(float4*)(&qs[r][hq*4]) = *(const float4*)(qb + (size_t)r * 512 + hq * 4);
    }
    __syncthreads();

    const int wave = t >> 6, lane = t & 63;
    float* wbase = wts + (size_t)cb * 1048576 + (size_t)m0 * 1024;

#pragma unroll 1
    for (int pr = 0; pr < 16; ++pr) {
        const int r0 = wave * 32 + pr * 2;   // row within 256-tile
        float qreg[2][16];
#pragma unroll
        for (int rr = 0; rr < 2; ++rr)
#pragma unroll
            for (int hq = 0; hq < 4; ++hq) {
                float4 qv = *(const float4*)(&qs[r0 + rr][hq * 4]);
                qreg[rr][hq*4+0] = qv.x; qreg[rr][hq*4+1] = qv.y;
                qreg[rr][hq*4+2] = qv.z; qreg[rr][hq*4+3] = qv.w;
            }
        float e[2][16];
        float sum[2] = {0.f, 0.f};
#pragma unroll
        for (int i = 0; i < 4; ++i) {
            const int n4 = i * 256 + lane * 4;
            float s0[4] = {}, s1[4] = {};
#pragma unroll
            for (int h = 0; h < 16; ++h) {
                float4 kv = *(const float4*)(&khT[h][n4]);
                float q0 = qreg[0][h], q1 = qreg[1][h];
                s0[0] += q0 * kv.x; s0[1] += q0 * kv.y;
                s0[2] += q0 * kv.z; s0[3] += q0 * kv.w;
                s1[0] += q1 * kv.x; s1[1] += q1 * kv.y;
                s1[2] += q1 * kv.z; s1[3] += q1 * kv.w;
            }
#pragma unroll
            for (int j = 0; j < 4; ++j) {
                e[0][i*4+j] = __expf(s0[j] * 0.25f); sum[0] += e[0][i*4+j];
                e[1][i*4+j] = __expf(s1[j] * 0.25f); sum[1] += e[1][i*4+j];
            }
        }
        float inv[2];
#pragma unroll
        for (int rr = 0; rr < 2; ++rr) {
            float s = sum[rr];
#pragma unroll
            for (int off = 32; off; off >>= 1) s += __shfl_xor(s, off);
            inv[rr] = 1.0f / s;
        }
        // fold normalization into e (consumed by both outputs)
#pragma unroll
        for (int x = 0; x < 16; ++x) { e[0][x] *= inv[0]; e[1][x] *= inv[1]; }
        // coalesced float4 weights store
#pragma unroll
        for (int rr = 0; rr < 2; ++rr) {
            float* wrow = wbase + (size_t)(r0 + rr) * 1024;
#pragma unroll
            for (int i = 0; i < 4; ++i)
                *(float4*)(&wrow[i * 256 + lane * 4]) =
                    make_float4(e[rr][i*4+0], e[rr][i*4+1], e[rr][i*4+2], e[rr][i*4+3]);
        }
        // PV partials over this lane's n subset
        float part[2][16] = {};
#pragma unroll
        for (int i = 0; i < 4; ++i) {
            const int n4 = i * 256 + lane * 4;
#pragma unroll
            for (int h = 0; h < 16; ++h) {
                float4 vv = *(const float4*)(&vsT[h][n4]);
                part[0][h] += e[0][i*4+0]*vv.x + e[0][i*4+1]*vv.y
                            + e[0][i*4+2]*vv.z + e[0][i*4+3]*vv.w;
                part[1][h] += e[1][i*4+0]*vv.x + e[1][i*4+1]*vv.y
                            + e[1][i*4+2]*vv.z + e[1][i*4+3]*vv.w;
            }
        }
        // reduce-scatter butterfly: 32 values, 5 steps; lane L ends with
        // j = L&31 summed over its 32-lane half; xor-32 completes 64-lane sum.
        float w[32];
#pragma unroll
        for (int rr = 0; rr < 2; ++rr)
#pragma unroll
            for (int h = 0; h < 16; ++h)
                w[rr * 16 + h] = part[rr][h];
#pragma unroll
        for (int s = 0; s < 5; ++s) {
            const int msk = 1 << s;
            const int bit = (lane >> s) & 1;
            const int cnt = 32 >> s;
#pragma unroll
            for (int u = 0; u < cnt / 2; ++u) {
                float a  = w[2 * u];
                float bb = w[2 * u + 1];
                float keep = bit ? bb : a;
                float send = bit ? a : bb;
                w[u] = keep + __shfl_xor(send, msk);
            }
        }
        w[0] += __shfl_xor(w[0], 32);
        // scrambled att write from lanes 0..31
        if (lane < 32) {
            const int m  = m0 + r0 + (lane >> 4);
            const int h  = lane & 15;
            const int b2 = c >> 4;
            const int m2 = (c & 15) * 64 + (m >> 4);
            const int d2 = (m & 15) * 32 + b * 16 + h;
            att[((size_t)b2 * 1024 + m2) * 512 + d2] = w[0];
        }
    }
}

// ---------------------------------------------------------------------------
extern "C" void kernel_launch(void* const* d_in, const int* in_sizes, int n_in,
                              void* d_out, int out_size, void* d_ws, size_t ws_size,
                              hipStream_t stream)
{
    (void)in_sizes; (void)n_in; (void)out_size; (void)ws_size;
    const float* Q  = (const float*)d_in[0];
    const float* K  = (const float*)d_in[1];
    const float* V  = (const float*)d_in[2];
    const float* Wq = (const float*)d_in[3];
    const float* Wk = (const float*)d_in[4];
    const float* Wv = (const float*)d_in[5];
    const float* Wo = (const float*)d_in[6];

    float* out = (float*)d_out;
    float* wts = out + 1048576;            // weights output region (64M floats)

    float* ws  = (float*)d_ws;
    float* q   = ws;                        // 1M floats
    float* k   = ws + (1u << 20);           // 1M
    float* v   = ws + 2 * (1u << 20);       // 1M
    float* att = ws + 3 * (1u << 20);       // 1M (scrambled out_pre)

    proj3_kernel<<<dim3(8, 32, 3), 256, 0, stream>>>(Q, K, V, Wq, Wk, Wv, q, k, v);
    attn_fused_kernel<<<256, 512, 0, stream>>>(q, k, v, wts, att);
    outproj_kernel<<<dim3(8, 32, 1), 256, 0, stream>>>(att, Wo, out);
}

// Round 4
// 290.080 us; speedup vs baseline: 2.5539x; 2.5539x over previous
//
#include <hip/hip_runtime.h>
#include <cstdint>
#include <cstddef>

// B=2, S=1024, D=512, NH=16 (chunk width), C=32 chunks.
// weights output (C,B,S,S) fp32 = 256 MiB written once, never re-read (PV fused).
// out_pre scramble: (c,b,m,h) -> [c>>4][(c&15)*64 + (m>>4)][(m&15)*32 + b*16 + h]

// ---------------------------------------------------------------------------
// NT GEMM body: P[M][512] = X[M][512] * W[512][512]^T   (tiles 64x64x32)
// ---------------------------------------------------------------------------
__device__ __forceinline__ void gemm_nt_body(const float* __restrict__ X,
                                             const float* __restrict__ W,
                                             float* __restrict__ P)
{
    __shared__ float As[32][68];
    __shared__ float Bs[32][68];
    const int t  = threadIdx.x;
    const int tx = t & 15, ty = t >> 4;
    const int m0 = blockIdx.y << 6;
    const int n0 = blockIdx.x << 6;
    float acc[4][4] = {};
    for (int k0 = 0; k0 < 512; k0 += 32) {
#pragma unroll
        for (int rep = 0; rep < 2; ++rep) {
            int f  = rep * 256 + t;
            int r  = f >> 3, c4 = f & 7;
            float4 xv = *(const float4*)(X + (size_t)(m0 + r) * 512 + k0 + c4 * 4);
            As[c4 * 4 + 0][r] = xv.x; As[c4 * 4 + 1][r] = xv.y;
            As[c4 * 4 + 2][r] = xv.z; As[c4 * 4 + 3][r] = xv.w;
            float4 wv = *(const float4*)(W + (size_t)(n0 + r) * 512 + k0 + c4 * 4);
            Bs[c4 * 4 + 0][r] = wv.x; Bs[c4 * 4 + 1][r] = wv.y;
            Bs[c4 * 4 + 2][r] = wv.z; Bs[c4 * 4 + 3][r] = wv.w;
        }
        __syncthreads();
#pragma unroll
        for (int kk = 0; kk < 32; ++kk) {
            float4 av = *(const float4*)(&As[kk][ty * 4]);
            float4 bv = *(const float4*)(&Bs[kk][tx * 4]);
            float a[4] = {av.x, av.y, av.z, av.w};
            float b[4] = {bv.x, bv.y, bv.z, bv.w};
#pragma unroll
            for (int i = 0; i < 4; ++i)
#pragma unroll
                for (int j = 0; j < 4; ++j)
                    acc[i][j] += a[i] * b[j];
        }
        __syncthreads();
    }
#pragma unroll
    for (int i = 0; i < 4; ++i) {
        float4 o = make_float4(acc[i][0], acc[i][1], acc[i][2], acc[i][3]);
        *(float4*)(P + (size_t)(m0 + ty * 4 + i) * 512 + n0 + tx * 4) = o;
    }
}

__global__ __launch_bounds__(256, 2) void proj3_kernel(
    const float* __restrict__ Q, const float* __restrict__ K, const float* __restrict__ V,
    const float* __restrict__ Wq, const float* __restrict__ Wk, const float* __restrict__ Wv,
    float* __restrict__ q, float* __restrict__ k, float* __restrict__ v)
{
    const float* X; const float* W; float* P;
    if (blockIdx.z == 0)      { X = Q; W = Wq; P = q; }
    else if (blockIdx.z == 1) { X = K; W = Wk; P = k; }
    else                      { X = V; W = Wv; P = v; }
    gemm_nt_body(X, W, P);
}

__global__ __launch_bounds__(256, 2) void outproj_kernel(
    const float* __restrict__ att, const float* __restrict__ Wo, float* __restrict__ out)
{
    gemm_nt_body(att, Wo, out);
}

// ---------------------------------------------------------------------------
// Fused scores + softmax + weights-write + PV.  v3:
//  - 4 rows/pass (8 passes/wave), float4 n-mapping, ds_read_b128 everywhere.
//  - amdgpu_waves_per_eu(2,2): LDS (144 KiB) already caps us at 1 block/CU
//    (= 2 waves/SIMD), so claim the full 256-VGPR budget -> no scratch spill.
//    (Round 2/3 lesson: compiler picks 128 VGPRs and spills catastrophically.)
//  - butterfly reduces part[64] IN PLACE (no extra w[] copy).
// Block = (c, b, 256-row tile), 512 threads, grid = 256 (1 block/CU).
// LDS: khT[16][1024] + vsT[16][1024] + qs[256][16] = 144 KiB.
// ---------------------------------------------------------------------------
__global__ __launch_bounds__(512)
__attribute__((amdgpu_waves_per_eu(2, 2)))
void attn_fused_kernel(
    const float* __restrict__ q, const float* __restrict__ k, const float* __restrict__ v,
    float* __restrict__ wts, float* __restrict__ att)
{
    __shared__ float khT[16][1024];
    __shared__ float vsT[16][1024];
    __shared__ float qs[256][16];
    const int t   = threadIdx.x;
    const int bid = blockIdx.x;       // 256 blocks
    const int mt  = bid & 3;          // 4 row tiles of 256
    const int cb  = bid >> 2;         // c*2 + b
    const int b   = cb & 1;
    const int c   = cb >> 1;
    const int m0  = mt << 8;

    const float* kb = k + (size_t)b * 524288 + c * 16;
    const float* vb = v + (size_t)b * 524288 + c * 16;
    const float* qb = q + (size_t)b * 524288 + (size_t)m0 * 512 + c * 16;

#pragma unroll
    for (int rep = 0; rep < 8; ++rep) {
        int f = rep * 512 + t;        // 4096 float4-slots
        int n = f >> 2, hq = f & 3;
        float4 kv = *(const float4*)(kb + (size_t)n * 512 + hq * 4);
        khT[hq*4+0][n] = kv.x; khT[hq*4+1][n] = kv.y;
        khT[hq*4+2][n] = kv.z; khT[hq*4+3][n] = kv.w;
        float4 vv = *(const float4*)(vb + (size_t)n * 512 + hq * 4);
        vsT[hq*4+0][n] = vv.x; vsT[hq*4+1][n] = vv.y;
        vsT[hq*4+2][n] = vv.z; vsT[hq*4+3][n] = vv.w;
    }
#pragma unroll
    for (int rep = 0; rep < 2; ++rep) {
        int f = rep * 512 + t;        // 1024 float4-slots
        int r = f >> 2, hq = f & 3;
        *(float4*)(&qs[r][hq*4]) = *(const float4*)(qb + (size_t)r * 512 + hq * 4);
    }
    __syncthreads();

    const int wave = t >> 6, lane = t & 63;
    float* wbase = wts + (size_t)cb * 1048576 + (size_t)m0 * 1024;

#pragma unroll 1
    for (int pq = 0; pq < 8; ++pq) {
        const int r0 = wave * 32 + pq * 4;   // row within 256-tile
        float qreg[4][16];
#pragma unroll
        for (int rr = 0; rr < 4; ++rr)
#pragma unroll
            for (int hq = 0; hq < 4; ++hq) {
                float4 qv = *(const float4*)(&qs[r0 + rr][hq * 4]);
                qreg[rr][hq*4+0] = qv.x; qreg[rr][hq*4+1] = qv.y;
                qreg[rr][hq*4+2] = qv.z; qreg[rr][hq*4+3] = qv.w;
            }
        // ---- scores + exp (e kept in regs) ----
        float e[4][16];
        float sum[4] = {0.f, 0.f, 0.f, 0.f};
#pragma unroll
        for (int i = 0; i < 4; ++i) {
            const int n4 = i * 256 + lane * 4;
            float s0[4] = {}, s1[4] = {}, s2[4] = {}, s3[4] = {};
#pragma unroll
            for (int h = 0; h < 16; ++h) {
                float4 kv = *(const float4*)(&khT[h][n4]);
                float q0 = qreg[0][h], q1 = qreg[1][h];
                float q2 = qreg[2][h], q3 = qreg[3][h];
                s0[0] += q0*kv.x; s0[1] += q0*kv.y; s0[2] += q0*kv.z; s0[3] += q0*kv.w;
                s1[0] += q1*kv.x; s1[1] += q1*kv.y; s1[2] += q1*kv.z; s1[3] += q1*kv.w;
                s2[0] += q2*kv.x; s2[1] += q2*kv.y; s2[2] += q2*kv.z; s2[3] += q2*kv.w;
                s3[0] += q3*kv.x; s3[1] += q3*kv.y; s3[2] += q3*kv.z; s3[3] += q3*kv.w;
            }
#pragma unroll
            for (int j = 0; j < 4; ++j) {
                e[0][i*4+j] = __expf(s0[j] * 0.25f); sum[0] += e[0][i*4+j];
                e[1][i*4+j] = __expf(s1[j] * 0.25f); sum[1] += e[1][i*4+j];
                e[2][i*4+j] = __expf(s2[j] * 0.25f); sum[2] += e[2][i*4+j];
                e[3][i*4+j] = __expf(s3[j] * 0.25f); sum[3] += e[3][i*4+j];
            }
        }
        // ---- row sums + normalization folded into e ----
#pragma unroll
        for (int rr = 0; rr < 4; ++rr) {
            float s = sum[rr];
#pragma unroll
            for (int off = 32; off; off >>= 1) s += __shfl_xor(s, off);
            float iv = 1.0f / s;
#pragma unroll
            for (int x = 0; x < 16; ++x) e[rr][x] *= iv;
        }
        // ---- coalesced float4 weights store ----
#pragma unroll
        for (int rr = 0; rr < 4; ++rr) {
            float* wrow = wbase + (size_t)(r0 + rr) * 1024;
#pragma unroll
            for (int i = 0; i < 4; ++i)
                *(float4*)(&wrow[i * 256 + lane * 4]) =
                    make_float4(e[rr][i*4+0], e[rr][i*4+1], e[rr][i*4+2], e[rr][i*4+3]);
        }
        // ---- PV partials (normalized e) ----
        float part[64] = {};
#pragma unroll
        for (int i = 0; i < 4; ++i) {
            const int n4 = i * 256 + lane * 4;
#pragma unroll
            for (int h = 0; h < 16; ++h) {
                float4 vv = *(const float4*)(&vsT[h][n4]);
                part[0*16+h] += e[0][i*4+0]*vv.x + e[0][i*4+1]*vv.y
                              + e[0][i*4+2]*vv.z + e[0][i*4+3]*vv.w;
                part[1*16+h] += e[1][i*4+0]*vv.x + e[1][i*4+1]*vv.y
                              + e[1][i*4+2]*vv.z + e[1][i*4+3]*vv.w;
                part[2*16+h] += e[2][i*4+0]*vv.x + e[2][i*4+1]*vv.y
                              + e[2][i*4+2]*vv.z + e[2][i*4+3]*vv.w;
                part[3*16+h] += e[3][i*4+0]*vv.x + e[3][i*4+1]*vv.y
                              + e[3][i*4+2]*vv.z + e[3][i*4+3]*vv.w;
            }
        }
        // ---- 6-step reduce-scatter butterfly IN PLACE on part[64] ----
        // (round-1-verified: lane L ends holding sum over all lanes of
        //  original part[L]; L = rr*16 + h)
#pragma unroll
        for (int s = 0; s < 6; ++s) {
            const int msk = 1 << s;
            const int bit = (lane >> s) & 1;
            const int cnt = 64 >> s;
#pragma unroll
            for (int u = 0; u < cnt / 2; ++u) {
                float a  = part[2 * u];
                float bb = part[2 * u + 1];
                float keep = bit ? bb : a;
                float send = bit ? a : bb;
                part[u] = keep + __shfl_xor(send, msk);
            }
        }
        // ---- scrambled att write: one float per lane ----
        const int m  = m0 + r0 + (lane >> 4);
        const int h  = lane & 15;
        const int b2 = c >> 4;
        const int m2 = (c & 15) * 64 + (m >> 4);
        const int d2 = (m & 15) * 32 + b * 16 + h;
        att[((size_t)b2 * 1024 + m2) * 512 + d2] = part[0];
    }
}

// ---------------------------------------------------------------------------
extern "C" void kernel_launch(void* const* d_in, const int* in_sizes, int n_in,
                              void* d_out, int out_size, void* d_ws, size_t ws_size,
                              hipStream_t stream)
{
    (void)in_sizes; (void)n_in; (void)out_size; (void)ws_size;
    const float* Q  = (const float*)d_in[0];
    const float* K  = (const float*)d_in[1];
    const float* V  = (const float*)d_in[2];
    const float* Wq = (const float*)d_in[3];
    const float* Wk = (const float*)d_in[4];
    const float* Wv = (const float*)d_in[5];
    const float* Wo = (const float*)d_in[6];

    float* out = (float*)d_out;
    float* wts = out + 1048576;            // weights output region (64M floats)

    float* ws  = (float*)d_ws;
    float* q   = ws;                        // 1M floats
    float* k   = ws + (1u << 20);           // 1M
    float* v   = ws + 2 * (1u << 20);       // 1M
    float* att = ws + 3 * (1u << 20);       // 1M (scrambled out_pre)

    proj3_kernel<<<dim3(8, 32, 3), 256, 0, stream>>>(Q, K, V, Wq, Wk, Wv, q, k, v);
    attn_fused_kernel<<<256, 512, 0, stream>>>(q, k, v, wts, att);
    outproj_kernel<<<dim3(8, 32, 1), 256, 0, stream>>>(att, Wo, out);
}